// Round 2
// baseline (1147.727 us; speedup 1.0000x reference)
//
#include <hip/hip_runtime.h>
#include <hip/hip_bf16.h>

// Problem constants
#define BB 2
#define TT 2048
#define CC 1024
#define HH 16
#define DD 64
#define MM (BB * TT)   // 4096 rows

typedef __bf16 bf16;
typedef __bf16 bf16x8 __attribute__((ext_vector_type(8)));
typedef float f32x4 __attribute__((ext_vector_type(4)));

// ---------------------------------------------------------------------------
// Runtime input-dtype probe. Views the first 2048 halfwords of q as bf16.
// Sane bf16 activations (N(0,1)-ish) never have exponent >= 0xC0 (|x|>=2^65);
// fp32-underlying data puts random mantissa bits in the low halfwords (~25%
// of which exceed that). flag: 0 = inputs are bf16, 1 = inputs are fp32.
// ---------------------------------------------------------------------------
__global__ __launch_bounds__(256) void detect_dtype(
    const unsigned short* __restrict__ q, int* __restrict__ flag)
{
    __shared__ int cnt;
    if (threadIdx.x == 0) cnt = 0;
    __syncthreads();
    int bad = 0;
#pragma unroll
    for (int i = 0; i < 8; ++i) {
        const unsigned short u = q[threadIdx.x * 8 + i];
        const int e = (u >> 7) & 0xFF;
        if (e >= 0xC0) ++bad;
    }
    atomicAdd(&cnt, bad);
    __syncthreads();
    if (threadIdx.x == 0) *flag = (cnt >= 8) ? 1 : 0;
}

// ---------------------------------------------------------------------------
// 8-element fragment loader -> bf16x8 (converts fp32 -> bf16 on the fly)
// ---------------------------------------------------------------------------
template <typename T>
__device__ __forceinline__ bf16x8 load8(const T* p);

template <>
__device__ __forceinline__ bf16x8 load8<bf16>(const bf16* p) {
    return *reinterpret_cast<const bf16x8*>(p);
}
template <>
__device__ __forceinline__ bf16x8 load8<float>(const float* p) {
    const f32x4 a = *reinterpret_cast<const f32x4*>(p);
    const f32x4 b = *reinterpret_cast<const f32x4*>(p + 4);
    bf16x8 r;
#pragma unroll
    for (int j = 0; j < 4; ++j) { r[j] = (bf16)a[j]; r[j + 4] = (bf16)b[j]; }
    return r;
}

// ---------------------------------------------------------------------------
// Y = X @ W^T + bias GEMM, fp32 accum via MFMA 16x16x32 bf16.
// One 16x16 output tile per wave, fragments loaded directly from global.
// A/B frags: lane reads row (tile0 + (lane&15)), 8 elems at k = (lane>>4)*8.
// C/D layout: col = lane&15, row = (lane>>4)*4 + r   [verified m89/m91]
// HEAD_LAYOUT=1: write to [B,H,T,D]; else flat [M,C].
// Self-gates on *flag == want (dtype dispatch).
// ---------------------------------------------------------------------------
template <typename TX, typename TW, typename TOUT, int HEAD_LAYOUT>
__global__ __launch_bounds__(256) void gemm_xwt(
    const TX* __restrict__ X, const TW* __restrict__ W,
    const TW* __restrict__ bias, TOUT* __restrict__ out,
    const int* __restrict__ flag, int want)
{
    if (*flag != want) return;

    const int tid  = threadIdx.x;
    const int lane = tid & 63;
    const int wave = tid >> 6;
    const int tile = blockIdx.x * 4 + wave;       // 16384 tiles total
    const int m0 = (tile >> 6) << 4;
    const int n0 = (tile & 63) << 4;
    const int lm   = lane & 15;
    const int koff = (lane >> 4) * 8;

    const TX* pa = X + (size_t)(m0 + lm) * CC + koff;
    const TW* pb = W + (size_t)(n0 + lm) * CC + koff;

    f32x4 acc = {0.f, 0.f, 0.f, 0.f};
#pragma unroll 8
    for (int kk = 0; kk < CC; kk += 32) {
        bf16x8 a = load8<TX>(pa + kk);
        bf16x8 b = load8<TW>(pb + kk);
        acc = __builtin_amdgcn_mfma_f32_16x16x32_bf16(a, b, acc, 0, 0, 0);
    }

    const int col = n0 + lm;
    const float bv = (float)bias[col];
#pragma unroll
    for (int r = 0; r < 4; ++r) {
        const int m = m0 + (lane >> 4) * 4 + r;
        const float v = acc[r] + bv;
        if (HEAD_LAYOUT) {
            const int b_ = m / TT, t = m % TT;
            const int h = col / DD, d = col % DD;
            out[(((size_t)(b_ * HH + h)) * TT + t) * DD + d] = (TOUT)v;
        } else {
            out[(size_t)m * CC + col] = (TOUT)v;
        }
    }
}

// ---------------------------------------------------------------------------
// Fused causal attention, flash-style online softmax. (dtype-independent:
// reads bf16 intermediates from workspace only.)
// Grid: (T/64, B*H). Block: 256 threads = 4 waves; wave w owns 16 Q rows.
// ---------------------------------------------------------------------------
__global__ __launch_bounds__(256) void attn_fused(
    const bf16* __restrict__ Qh, const bf16* __restrict__ Kh,
    const bf16* __restrict__ Vh, bf16* __restrict__ attn_out)
{
    __shared__ bf16 ldsVt[64 * 72];     // V^T tile: [d][key], +8 pad
    __shared__ bf16 ldsP[4][16 * 72];   // per-wave P tile: [q][key], +8 pad

    const int tid  = threadIdx.x;
    const int lane = tid & 63;
    const int wave = tid >> 6;
    const int qb = blockIdx.x;
    const int bh = blockIdx.y;
    const size_t base = (size_t)bh * TT * DD;
    const int q0 = qb * 64 + wave * 16;
    const int lm   = lane & 15;
    const int quad = lane >> 4;
    const int koff = quad * 8;
    const float scale = 0.125f;         // 1/sqrt(64)

    const bf16* qp = Qh + base + (size_t)(q0 + lm) * DD + koff;
    bf16x8 qf0 = *reinterpret_cast<const bf16x8*>(qp);
    bf16x8 qf1 = *reinterpret_cast<const bf16x8*>(qp + 32);

    f32x4 Oacc[4];
#pragma unroll
    for (int nt = 0; nt < 4; ++nt) Oacc[nt] = (f32x4){0.f, 0.f, 0.f, 0.f};
    float m_run[4] = {-1e30f, -1e30f, -1e30f, -1e30f};
    float l_run[4] = {0.f, 0.f, 0.f, 0.f};

    const int nkb = qb + 1;             // causal: key blocks 0..qb
    for (int kb = 0; kb < nkb; ++kb) {
        const int s0 = kb * 64;
        __syncthreads();
#pragma unroll
        for (int it = 0; it < 2; ++it) {
            const int slot = tid + it * 256;
            const int key = slot >> 3;
            const int dg = (slot & 7) * 8;
            bf16x8 v = *reinterpret_cast<const bf16x8*>(
                Vh + base + (size_t)(s0 + key) * DD + dg);
#pragma unroll
            for (int j = 0; j < 8; ++j) ldsVt[(dg + j) * 72 + key] = v[j];
        }
        __syncthreads();

        // S = Q K^T for 16 q-rows x 64 keys
        float sv[4][4];
#pragma unroll
        for (int st = 0; st < 4; ++st) {
            const bf16* kp = Kh + base + (size_t)(s0 + st * 16 + lm) * DD + koff;
            bf16x8 k0 = *reinterpret_cast<const bf16x8*>(kp);
            bf16x8 k1 = *reinterpret_cast<const bf16x8*>(kp + 32);
            f32x4 s = {0.f, 0.f, 0.f, 0.f};
            s = __builtin_amdgcn_mfma_f32_16x16x32_bf16(qf0, k0, s, 0, 0, 0);
            s = __builtin_amdgcn_mfma_f32_16x16x32_bf16(qf1, k1, s, 0, 0, 0);
            const int skey = s0 + st * 16 + lm;
#pragma unroll
            for (int r = 0; r < 4; ++r) {
                const int q = q0 + quad * 4 + r;
                sv[st][r] = (skey <= q) ? s[r] * scale : -1e30f;
            }
        }

        // online softmax over the quad's 16 lanes (butterfly all-reduce)
#pragma unroll
        for (int r = 0; r < 4; ++r) {
            float mx = fmaxf(fmaxf(sv[0][r], sv[1][r]),
                             fmaxf(sv[2][r], sv[3][r]));
            for (int off = 1; off < 16; off <<= 1)
                mx = fmaxf(mx, __shfl_xor(mx, off));
            const float mn = fmaxf(m_run[r], mx);
            const float alpha = __expf(m_run[r] - mn);
            m_run[r] = mn;
            float srow = 0.f;
#pragma unroll
            for (int st = 0; st < 4; ++st) {
                const float p = __expf(sv[st][r] - mn);
                sv[st][r] = p;
                srow += p;
            }
            for (int off = 1; off < 16; off <<= 1)
                srow += __shfl_xor(srow, off);
            l_run[r] = l_run[r] * alpha + srow;
#pragma unroll
            for (int nt = 0; nt < 4; ++nt) Oacc[nt][r] *= alpha;
        }

        // P: C-layout -> LDS -> A-layout (per-wave private region)
#pragma unroll
        for (int st = 0; st < 4; ++st)
#pragma unroll
            for (int r = 0; r < 4; ++r)
                ldsP[wave][(quad * 4 + r) * 72 + st * 16 + lm] =
                    (bf16)sv[st][r];

        // O += P V
#pragma unroll
        for (int kc = 0; kc < 64; kc += 32) {
            bf16x8 pf = *reinterpret_cast<const bf16x8*>(
                &ldsP[wave][lm * 72 + kc + koff]);
#pragma unroll
            for (int nt = 0; nt < 4; ++nt) {
                bf16x8 vf = *reinterpret_cast<const bf16x8*>(
                    &ldsVt[(nt * 16 + lm) * 72 + kc + koff]);
                Oacc[nt] = __builtin_amdgcn_mfma_f32_16x16x32_bf16(
                    pf, vf, Oacc[nt], 0, 0, 0);
            }
        }
    }

    // epilogue: O /= l, write bf16 to [M, C] flat
    const int b_ = bh / HH, h = bh % HH;
#pragma unroll
    for (int nt = 0; nt < 4; ++nt)
#pragma unroll
        for (int r = 0; r < 4; ++r) {
            const int q = q0 + quad * 4 + r;
            const int d = nt * 16 + lm;
            const float v = Oacc[nt][r] / l_run[r];
            attn_out[((size_t)(b_ * TT + q)) * CC + h * DD + d] = (bf16)v;
        }
}

// ---------------------------------------------------------------------------
extern "C" void kernel_launch(void* const* d_in, const int* in_sizes, int n_in,
                              void* d_out, int out_size, void* d_ws,
                              size_t ws_size, hipStream_t stream)
{
    // workspace layout: flag (16 B) | Qh | Kh | Vh ([B,H,T,D] bf16) | attn
    int* flag = (int*)d_ws;
    bf16* Qh = (bf16*)((char*)d_ws + 16);
    bf16* Kh = Qh + (size_t)MM * CC;
    bf16* Vh = Kh + (size_t)MM * CC;
    bf16* attn = Vh + (size_t)MM * CC;

    const dim3 blk(256);
    const int gemm_blocks = (MM / 16) * (CC / 16) / 4;  // 4096

    detect_dtype<<<1, blk, 0, stream>>>((const unsigned short*)d_in[0], flag);

    // ---- bf16-input path (flag == 0) ----
    gemm_xwt<bf16, bf16, bf16, 1><<<gemm_blocks, blk, 0, stream>>>(
        (const bf16*)d_in[0], (const bf16*)d_in[4], (const bf16*)d_in[5], Qh, flag, 0);
    gemm_xwt<bf16, bf16, bf16, 1><<<gemm_blocks, blk, 0, stream>>>(
        (const bf16*)d_in[1], (const bf16*)d_in[6], (const bf16*)d_in[7], Kh, flag, 0);
    gemm_xwt<bf16, bf16, bf16, 1><<<gemm_blocks, blk, 0, stream>>>(
        (const bf16*)d_in[2], (const bf16*)d_in[8], (const bf16*)d_in[9], Vh, flag, 0);

    // ---- fp32-input path (flag == 1) ----
    gemm_xwt<float, float, bf16, 1><<<gemm_blocks, blk, 0, stream>>>(
        (const float*)d_in[0], (const float*)d_in[4], (const float*)d_in[5], Qh, flag, 1);
    gemm_xwt<float, float, bf16, 1><<<gemm_blocks, blk, 0, stream>>>(
        (const float*)d_in[1], (const float*)d_in[6], (const float*)d_in[7], Kh, flag, 1);
    gemm_xwt<float, float, bf16, 1><<<gemm_blocks, blk, 0, stream>>>(
        (const float*)d_in[2], (const float*)d_in[8], (const float*)d_in[9], Vh, flag, 1);

    // ---- attention core (dtype-independent) ----
    attn_fused<<<dim3(TT / 64, BB * HH), blk, 0, stream>>>(Qh, Kh, Vh, attn);

    // ---- output projection ----
    gemm_xwt<bf16, bf16, bf16, 0><<<gemm_blocks, blk, 0, stream>>>(
        attn, (const bf16*)d_in[10], (const bf16*)d_in[11], (bf16*)d_out, flag, 0);
    gemm_xwt<bf16, float, float, 0><<<gemm_blocks, blk, 0, stream>>>(
        attn, (const float*)d_in[10], (const float*)d_in[11], (float*)d_out, flag, 1);
}

// Round 6
// 610.469 us; speedup vs baseline: 1.8801x; 1.8801x over previous
//
#include <hip/hip_runtime.h>
#include <hip/hip_bf16.h>

// Problem constants
#define BB 2
#define TT 2048
#define CC 1024
#define HH 16
#define DD 64
#define MM (BB * TT)   // 4096 rows

typedef __bf16 bf16;
typedef __bf16 bf16x8 __attribute__((ext_vector_type(8)));
typedef float f32x4 __attribute__((ext_vector_type(4)));

// ---------------------------------------------------------------------------
// 8-element fragment loader -> bf16x8. fp32 variant converts on the fly
// (PROVEN in round 2's passing fp32 path).
// ---------------------------------------------------------------------------
template <typename T>
__device__ __forceinline__ bf16x8 load8(const T* p);

template <>
__device__ __forceinline__ bf16x8 load8<bf16>(const bf16* p) {
    return *reinterpret_cast<const bf16x8*>(p);
}
template <>
__device__ __forceinline__ bf16x8 load8<float>(const float* p) {
    const f32x4 a = *reinterpret_cast<const f32x4*>(p);
    const f32x4 b = *reinterpret_cast<const f32x4*>(p + 4);
    bf16x8 r;
#pragma unroll
    for (int j = 0; j < 4; ++j) { r[j] = (bf16)a[j]; r[j + 4] = (bf16)b[j]; }
    return r;
}

// ---------------------------------------------------------------------------
// Y = X @ W^T + bias, fp32 accum via MFMA 16x16x32 bf16 (inputs converted).
// Register-blocked: wave computes 4(M) x 2(N) 16x16 tiles; 4 waves split N
// -> 64x128 per block. Per-tile math identical to round-2's proven kernel:
// A/B frag: row = tile0 + (lane&15), k = (lane>>4)*8; C/D: col = lane&15,
// row = (lane>>4)*4 + r. No barriers; loads batch ahead of 8 MFMAs.
// HEAD_LAYOUT=1: write [B,H,T,D]; else flat [M,C].
// ---------------------------------------------------------------------------
template <typename TX, typename TW, typename TOUT, int HEAD_LAYOUT>
__global__ __launch_bounds__(256) void gemm_rb(
    const TX* __restrict__ X, const TW* __restrict__ W,
    const float* __restrict__ bias, TOUT* __restrict__ out)
{
    const int tid  = threadIdx.x;
    const int lane = tid & 63;
    const int wave = tid >> 6;
    const int lm   = lane & 15;
    const int quad = lane >> 4;
    const int koff = quad * 8;
    const int m0 = blockIdx.x * 64;                 // 4 m-tiles
    const int n0 = blockIdx.y * 128 + wave * 32;    // 2 n-tiles per wave

    const TX* pa = X + (size_t)(m0 + lm) * CC + koff;
    const TW* pb = W + (size_t)(n0 + lm) * CC + koff;

    f32x4 acc[4][2];
#pragma unroll
    for (int i = 0; i < 4; ++i)
#pragma unroll
        for (int j = 0; j < 2; ++j) acc[i][j] = (f32x4){0.f, 0.f, 0.f, 0.f};

    for (int kk = 0; kk < CC; kk += 32) {
        bf16x8 a[4], b[2];
#pragma unroll
        for (int i = 0; i < 4; ++i)
            a[i] = load8<TX>(pa + (size_t)i * 16 * CC + kk);
#pragma unroll
        for (int j = 0; j < 2; ++j)
            b[j] = load8<TW>(pb + (size_t)j * 16 * CC + kk);
#pragma unroll
        for (int i = 0; i < 4; ++i)
#pragma unroll
            for (int j = 0; j < 2; ++j)
                acc[i][j] = __builtin_amdgcn_mfma_f32_16x16x32_bf16(
                    a[i], b[j], acc[i][j], 0, 0, 0);
    }

#pragma unroll
    for (int j = 0; j < 2; ++j) {
        const int col = n0 + j * 16 + lm;
        const float bv = bias[col];
#pragma unroll
        for (int i = 0; i < 4; ++i)
#pragma unroll
            for (int r = 0; r < 4; ++r) {
                const int m = m0 + i * 16 + quad * 4 + r;
                const float v = acc[i][j][r] + bv;
                if (HEAD_LAYOUT) {
                    const int b_ = m / TT, t = m % TT;
                    const int h = col / DD, d = col % DD;
                    out[(((size_t)(b_ * HH + h)) * TT + t) * DD + d] = (TOUT)v;
                } else {
                    out[(size_t)m * CC + col] = (TOUT)v;
                }
            }
    }
}

// ---------------------------------------------------------------------------
// Fused causal attention — EXACT round-2 PROVEN kernel ([B,H,T,D] bf16
// intermediates); only inert change: q-tiles issued longest first.
// Grid: (T/64, B*H). Block: 256 = 4 waves; wave owns 16 Q rows.
// ---------------------------------------------------------------------------
__global__ __launch_bounds__(256) void attn_fused(
    const bf16* __restrict__ Qh, const bf16* __restrict__ Kh,
    const bf16* __restrict__ Vh, bf16* __restrict__ attn_out)
{
    __shared__ bf16 ldsVt[64 * 72];     // V^T tile: [d][key], +8 pad
    __shared__ bf16 ldsP[4][16 * 72];   // per-wave P tile: [q][key], +8 pad

    const int tid  = threadIdx.x;
    const int lane = tid & 63;
    const int wave = tid >> 6;
    const int qb = (TT / 64 - 1) - blockIdx.x;   // longest first
    const int bh = blockIdx.y;
    const size_t base = (size_t)bh * TT * DD;
    const int q0 = qb * 64 + wave * 16;
    const int lm   = lane & 15;
    const int quad = lane >> 4;
    const int koff = quad * 8;
    const float scale = 0.125f;         // 1/sqrt(64)

    const bf16* qp = Qh + base + (size_t)(q0 + lm) * DD + koff;
    bf16x8 qf0 = *reinterpret_cast<const bf16x8*>(qp);
    bf16x8 qf1 = *reinterpret_cast<const bf16x8*>(qp + 32);

    f32x4 Oacc[4];
#pragma unroll
    for (int nt = 0; nt < 4; ++nt) Oacc[nt] = (f32x4){0.f, 0.f, 0.f, 0.f};
    float m_run[4] = {-1e30f, -1e30f, -1e30f, -1e30f};
    float l_run[4] = {0.f, 0.f, 0.f, 0.f};

    const int nkb = qb + 1;             // causal: key blocks 0..qb
    for (int kb = 0; kb < nkb; ++kb) {
        const int s0 = kb * 64;
        __syncthreads();
#pragma unroll
        for (int it = 0; it < 2; ++it) {
            const int slot = tid + it * 256;
            const int key = slot >> 3;
            const int dg = (slot & 7) * 8;
            bf16x8 v = *reinterpret_cast<const bf16x8*>(
                Vh + base + (size_t)(s0 + key) * DD + dg);
#pragma unroll
            for (int j = 0; j < 8; ++j) ldsVt[(dg + j) * 72 + key] = v[j];
        }
        __syncthreads();

        // S = Q K^T for 16 q-rows x 64 keys
        float sv[4][4];
#pragma unroll
        for (int st = 0; st < 4; ++st) {
            const bf16* kp = Kh + base + (size_t)(s0 + st * 16 + lm) * DD + koff;
            bf16x8 k0 = *reinterpret_cast<const bf16x8*>(kp);
            bf16x8 k1 = *reinterpret_cast<const bf16x8*>(kp + 32);
            f32x4 s = {0.f, 0.f, 0.f, 0.f};
            s = __builtin_amdgcn_mfma_f32_16x16x32_bf16(qf0, k0, s, 0, 0, 0);
            s = __builtin_amdgcn_mfma_f32_16x16x32_bf16(qf1, k1, s, 0, 0, 0);
            const int skey = s0 + st * 16 + lm;
#pragma unroll
            for (int r = 0; r < 4; ++r) {
                const int q = q0 + quad * 4 + r;
                sv[st][r] = (skey <= q) ? s[r] * scale : -1e30f;
            }
        }

        // online softmax over the quad's 16 lanes (butterfly all-reduce)
#pragma unroll
        for (int r = 0; r < 4; ++r) {
            float mx = fmaxf(fmaxf(sv[0][r], sv[1][r]),
                             fmaxf(sv[2][r], sv[3][r]));
            for (int off = 1; off < 16; off <<= 1)
                mx = fmaxf(mx, __shfl_xor(mx, off));
            const float mn = fmaxf(m_run[r], mx);
            const float alpha = __expf(m_run[r] - mn);
            m_run[r] = mn;
            float srow = 0.f;
#pragma unroll
            for (int st = 0; st < 4; ++st) {
                const float p = __expf(sv[st][r] - mn);
                sv[st][r] = p;
                srow += p;
            }
            for (int off = 1; off < 16; off <<= 1)
                srow += __shfl_xor(srow, off);
            l_run[r] = l_run[r] * alpha + srow;
#pragma unroll
            for (int nt = 0; nt < 4; ++nt) Oacc[nt][r] *= alpha;
        }

        // P: C-layout -> LDS -> A-layout (per-wave private region)
#pragma unroll
        for (int st = 0; st < 4; ++st)
#pragma unroll
            for (int r = 0; r < 4; ++r)
                ldsP[wave][(quad * 4 + r) * 72 + st * 16 + lm] =
                    (bf16)sv[st][r];

        // O += P V
#pragma unroll
        for (int kc = 0; kc < 64; kc += 32) {
            bf16x8 pf = *reinterpret_cast<const bf16x8*>(
                &ldsP[wave][lm * 72 + kc + koff]);
#pragma unroll
            for (int nt = 0; nt < 4; ++nt) {
                bf16x8 vf = *reinterpret_cast<const bf16x8*>(
                    &ldsVt[(nt * 16 + lm) * 72 + kc + koff]);
                Oacc[nt] = __builtin_amdgcn_mfma_f32_16x16x32_bf16(
                    pf, vf, Oacc[nt], 0, 0, 0);
            }
        }
    }

    // epilogue: O /= l, write bf16 to [M, C] flat
    const int b_ = bh / HH, h = bh % HH;
#pragma unroll
    for (int nt = 0; nt < 4; ++nt)
#pragma unroll
        for (int r = 0; r < 4; ++r) {
            const int q = q0 + quad * 4 + r;
            const int d = nt * 16 + lm;
            const float v = Oacc[nt][r] / l_run[r];
            attn_out[((size_t)(b_ * TT + q)) * CC + h * DD + d] = (bf16)v;
        }
}

// ---------------------------------------------------------------------------
extern "C" void kernel_launch(void* const* d_in, const int* in_sizes, int n_in,
                              void* d_out, int out_size, void* d_ws,
                              size_t ws_size, hipStream_t stream)
{
    // Reference dtypes: ALL float tensors are fp32 (jnp.float32); mask int32.
    const float* q  = (const float*)d_in[0];
    const float* k  = (const float*)d_in[1];
    const float* v  = (const float*)d_in[2];
    // d_in[3] = causal mask — analytic
    const float* Wq = (const float*)d_in[4];
    const float* bq = (const float*)d_in[5];
    const float* Wk = (const float*)d_in[6];
    const float* bk = (const float*)d_in[7];
    const float* Wv = (const float*)d_in[8];
    const float* bv = (const float*)d_in[9];
    const float* Wo = (const float*)d_in[10];
    const float* bo = (const float*)d_in[11];
    float* out = (float*)d_out;            // fp32 output [M, C]

    // workspace: Qh | Kh | Vh ([B,H,T,D] bf16) | attn ([M,C] bf16) = 32 MB
    bf16* Qh = (bf16*)d_ws;
    bf16* Kh = Qh + (size_t)MM * CC;
    bf16* Vh = Kh + (size_t)MM * CC;
    bf16* attn = Vh + (size_t)MM * CC;

    const dim3 blk(256);
    const dim3 ggrid(MM / 64, CC / 128);   // 512 blocks

    gemm_rb<float, float, bf16, 1><<<ggrid, blk, 0, stream>>>(q, Wq, bq, Qh);
    gemm_rb<float, float, bf16, 1><<<ggrid, blk, 0, stream>>>(k, Wk, bk, Kh);
    gemm_rb<float, float, bf16, 1><<<ggrid, blk, 0, stream>>>(v, Wv, bv, Vh);
    attn_fused<<<dim3(TT / 64, BB * HH), blk, 0, stream>>>(Qh, Kh, Vh, attn);
    gemm_rb<bf16, float, float, 0><<<ggrid, blk, 0, stream>>>(attn, Wo, bo, out);
}

// Round 7
// 411.907 us; speedup vs baseline: 2.7864x; 1.4821x over previous
//
#include <hip/hip_runtime.h>
#include <hip/hip_bf16.h>

// Problem constants
#define BB 2
#define TT 2048
#define CC 1024
#define HH 16
#define DD 64
#define MM (BB * TT)   // 4096 rows

typedef __bf16 bf16;
typedef __bf16 bf16x8 __attribute__((ext_vector_type(8)));
typedef float f32x4 __attribute__((ext_vector_type(4)));

// ---------------------------------------------------------------------------
// 8-element fragment loader -> bf16x8 (fp32 variant converts on the fly).
// PROVEN in rounds 2/6.
// ---------------------------------------------------------------------------
template <typename T>
__device__ __forceinline__ bf16x8 load8(const T* p);

template <>
__device__ __forceinline__ bf16x8 load8<bf16>(const bf16* p) {
    return *reinterpret_cast<const bf16x8*>(p);
}
template <>
__device__ __forceinline__ bf16x8 load8<float>(const float* p) {
    const f32x4 a = *reinterpret_cast<const f32x4*>(p);
    const f32x4 b = *reinterpret_cast<const f32x4*>(p + 4);
    bf16x8 r;
#pragma unroll
    for (int j = 0; j < 4; ++j) { r[j] = (bf16)a[j]; r[j + 4] = (bf16)b[j]; }
    return r;
}

// ---------------------------------------------------------------------------
// 128x128-tile GEMM body: Y = X @ W^T + bias, BK=32, fp32 accum, MFMA
// 16x16x32 bf16. X: [M x K] (fp32 or bf16), W: [N x K] fp32. 256 threads =
// 4 waves; wave owns a 64x64 quadrant = 4x4 MFMA tiles. Staging: global
// loads (converted to bf16 in regs) -> ds_write_b128; loads issue before
// the barrier so they overlap the previous K-step's MFMAs.
// LDS [row][32] unpadded; chunk c (8 elems) at lA+c*8 = row c>>2,
// k-offset (c&3)*8.  (r3 structure — NaN there was the input-dtype bug,
// since fixed; per-tile math identical to the r2/r6 proven kernels.)
// ---------------------------------------------------------------------------
template <typename TX, typename TOUT, int HEAD_LAYOUT>
__device__ __forceinline__ void gemm_tile_body(
    const TX* __restrict__ X, const float* __restrict__ W,
    const float* __restrict__ bias, TOUT* __restrict__ out,
    bf16* lA, bf16* lB)
{
    const int tid  = threadIdx.x;
    const int lane = tid & 63;
    const int quad = lane >> 4;
    const int lm   = lane & 15;
    const int wave = tid >> 6;
    const int m0 = blockIdx.x << 7;
    const int n0 = blockIdx.y << 7;
    const int wrow = (wave >> 1) << 6;  // 0 / 64
    const int wcol = (wave & 1) << 6;   // 0 / 64

    const int c0 = tid, c1 = tid + 256;           // 512 chunks per tile
    const TX*    gA0 = X + (size_t)(m0 + (c0 >> 2)) * CC + (c0 & 3) * 8;
    const TX*    gA1 = X + (size_t)(m0 + (c1 >> 2)) * CC + (c1 & 3) * 8;
    const float* gB0 = W + (size_t)(n0 + (c0 >> 2)) * CC + (c0 & 3) * 8;
    const float* gB1 = W + (size_t)(n0 + (c1 >> 2)) * CC + (c1 & 3) * 8;
    bf16* lA0 = lA + c0 * 8;  bf16* lA1 = lA + c1 * 8;
    bf16* lB0 = lB + c0 * 8;  bf16* lB1 = lB + c1 * 8;

    f32x4 acc[4][4];
#pragma unroll
    for (int i = 0; i < 4; ++i)
#pragma unroll
        for (int j = 0; j < 4; ++j) acc[i][j] = (f32x4){0.f, 0.f, 0.f, 0.f};

    for (int kk = 0; kk < CC; kk += 32) {
        // global loads first: latency overlaps previous K-step's MFMAs
        bf16x8 a0 = load8<TX>(gA0 + kk);
        bf16x8 a1 = load8<TX>(gA1 + kk);
        bf16x8 b0 = load8<float>(gB0 + kk);
        bf16x8 b1 = load8<float>(gB1 + kk);
        __syncthreads();                 // previous iteration's readers done
        *reinterpret_cast<bf16x8*>(lA0) = a0;
        *reinterpret_cast<bf16x8*>(lA1) = a1;
        *reinterpret_cast<bf16x8*>(lB0) = b0;
        *reinterpret_cast<bf16x8*>(lB1) = b1;
        __syncthreads();                 // writes visible to all waves

        bf16x8 af[4], bf_[4];
#pragma unroll
        for (int i = 0; i < 4; ++i)
            af[i] = *reinterpret_cast<const bf16x8*>(
                lA + (wrow + i * 16 + lm) * 32 + quad * 8);
#pragma unroll
        for (int j = 0; j < 4; ++j)
            bf_[j] = *reinterpret_cast<const bf16x8*>(
                lB + (wcol + j * 16 + lm) * 32 + quad * 8);
#pragma unroll
        for (int i = 0; i < 4; ++i)
#pragma unroll
            for (int j = 0; j < 4; ++j)
                acc[i][j] = __builtin_amdgcn_mfma_f32_16x16x32_bf16(
                    af[i], bf_[j], acc[i][j], 0, 0, 0);
    }

    // epilogue: C/D layout col = lane&15, row = quad*4 + r  [m89/m91]
#pragma unroll
    for (int j = 0; j < 4; ++j) {
        const int col = n0 + wcol + j * 16 + lm;
        const float bv = bias[col];
#pragma unroll
        for (int i = 0; i < 4; ++i)
#pragma unroll
            for (int r = 0; r < 4; ++r) {
                const int m = m0 + wrow + i * 16 + quad * 4 + r;
                const float v = acc[i][j][r] + bv;
                if (HEAD_LAYOUT) {
                    const int b_ = m / TT, t = m % TT;
                    const int h = col / DD, d = col % DD;
                    out[(((size_t)(b_ * HH + h)) * TT + t) * DD + d] = (TOUT)v;
                } else {
                    out[(size_t)m * CC + col] = (TOUT)v;
                }
            }
    }
}

// Fused Q/K/V projections: grid (M/128, C/128, 3); z selects the GEMM.
// 768 blocks ~ 3/CU so barrier drains overlap across blocks (m114).
__global__ __launch_bounds__(256) void gemm_qkv(
    const float* __restrict__ x0, const float* __restrict__ x1,
    const float* __restrict__ x2,
    const float* __restrict__ w0, const float* __restrict__ w1,
    const float* __restrict__ w2,
    const float* __restrict__ b0, const float* __restrict__ b1,
    const float* __restrict__ b2,
    bf16* __restrict__ o0, bf16* __restrict__ o1, bf16* __restrict__ o2)
{
    __shared__ __align__(16) bf16 lA[128 * 32];
    __shared__ __align__(16) bf16 lB[128 * 32];
    const int z = blockIdx.z;
    const float* X = (z == 0) ? x0 : (z == 1) ? x1 : x2;
    const float* W = (z == 0) ? w0 : (z == 1) ? w1 : w2;
    const float* bias = (z == 0) ? b0 : (z == 1) ? b1 : b2;
    bf16* out = (z == 0) ? o0 : (z == 1) ? o1 : o2;
    gemm_tile_body<float, bf16, 1>(X, W, bias, out, lA, lB);
}

// Output projection: X = attn ws (bf16 [M,C]), W/bias fp32, out fp32 [M,C].
__global__ __launch_bounds__(256) void gemm_oproj(
    const bf16* __restrict__ X, const float* __restrict__ W,
    const float* __restrict__ bias, float* __restrict__ out)
{
    __shared__ __align__(16) bf16 lA[128 * 32];
    __shared__ __align__(16) bf16 lB[128 * 32];
    gemm_tile_body<bf16, float, 0>(X, W, bias, out, lA, lB);
}

// ---------------------------------------------------------------------------
// Fused causal attention — EXACT round-6 PROVEN kernel, unchanged.
// [B,H,T,D] bf16 intermediates; q-tiles issued longest first.
// Grid: (T/64, B*H). Block: 256 = 4 waves; wave owns 16 Q rows.
// ---------------------------------------------------------------------------
__global__ __launch_bounds__(256) void attn_fused(
    const bf16* __restrict__ Qh, const bf16* __restrict__ Kh,
    const bf16* __restrict__ Vh, bf16* __restrict__ attn_out)
{
    __shared__ bf16 ldsVt[64 * 72];     // V^T tile: [d][key], +8 pad
    __shared__ bf16 ldsP[4][16 * 72];   // per-wave P tile: [q][key], +8 pad

    const int tid  = threadIdx.x;
    const int lane = tid & 63;
    const int wave = tid >> 6;
    const int qb = (TT / 64 - 1) - blockIdx.x;   // longest first
    const int bh = blockIdx.y;
    const size_t base = (size_t)bh * TT * DD;
    const int q0 = qb * 64 + wave * 16;
    const int lm   = lane & 15;
    const int quad = lane >> 4;
    const int koff = quad * 8;
    const float scale = 0.125f;         // 1/sqrt(64)

    const bf16* qp = Qh + base + (size_t)(q0 + lm) * DD + koff;
    bf16x8 qf0 = *reinterpret_cast<const bf16x8*>(qp);
    bf16x8 qf1 = *reinterpret_cast<const bf16x8*>(qp + 32);

    f32x4 Oacc[4];
#pragma unroll
    for (int nt = 0; nt < 4; ++nt) Oacc[nt] = (f32x4){0.f, 0.f, 0.f, 0.f};
    float m_run[4] = {-1e30f, -1e30f, -1e30f, -1e30f};
    float l_run[4] = {0.f, 0.f, 0.f, 0.f};

    const int nkb = qb + 1;             // causal: key blocks 0..qb
    for (int kb = 0; kb < nkb; ++kb) {
        const int s0 = kb * 64;
        __syncthreads();
#pragma unroll
        for (int it = 0; it < 2; ++it) {
            const int slot = tid + it * 256;
            const int key = slot >> 3;
            const int dg = (slot & 7) * 8;
            bf16x8 v = *reinterpret_cast<const bf16x8*>(
                Vh + base + (size_t)(s0 + key) * DD + dg);
#pragma unroll
            for (int j = 0; j < 8; ++j) ldsVt[(dg + j) * 72 + key] = v[j];
        }
        __syncthreads();

        // S = Q K^T for 16 q-rows x 64 keys
        float sv[4][4];
#pragma unroll
        for (int st = 0; st < 4; ++st) {
            const bf16* kp = Kh + base + (size_t)(s0 + st * 16 + lm) * DD + koff;
            bf16x8 k0 = *reinterpret_cast<const bf16x8*>(kp);
            bf16x8 k1 = *reinterpret_cast<const bf16x8*>(kp + 32);
            f32x4 s = {0.f, 0.f, 0.f, 0.f};
            s = __builtin_amdgcn_mfma_f32_16x16x32_bf16(qf0, k0, s, 0, 0, 0);
            s = __builtin_amdgcn_mfma_f32_16x16x32_bf16(qf1, k1, s, 0, 0, 0);
            const int skey = s0 + st * 16 + lm;
#pragma unroll
            for (int r = 0; r < 4; ++r) {
                const int q = q0 + quad * 4 + r;
                sv[st][r] = (skey <= q) ? s[r] * scale : -1e30f;
            }
        }

        // online softmax over the quad's 16 lanes (butterfly all-reduce)
#pragma unroll
        for (int r = 0; r < 4; ++r) {
            float mx = fmaxf(fmaxf(sv[0][r], sv[1][r]),
                             fmaxf(sv[2][r], sv[3][r]));
            for (int off = 1; off < 16; off <<= 1)
                mx = fmaxf(mx, __shfl_xor(mx, off));
            const float mn = fmaxf(m_run[r], mx);
            const float alpha = __expf(m_run[r] - mn);
            m_run[r] = mn;
            float srow = 0.f;
#pragma unroll
            for (int st = 0; st < 4; ++st) {
                const float p = __expf(sv[st][r] - mn);
                sv[st][r] = p;
                srow += p;
            }
            for (int off = 1; off < 16; off <<= 1)
                srow += __shfl_xor(srow, off);
            l_run[r] = l_run[r] * alpha + srow;
#pragma unroll
            for (int nt = 0; nt < 4; ++nt) Oacc[nt][r] *= alpha;
        }

        // P: C-layout -> LDS -> A-layout (per-wave private region)
#pragma unroll
        for (int st = 0; st < 4; ++st)
#pragma unroll
            for (int r = 0; r < 4; ++r)
                ldsP[wave][(quad * 4 + r) * 72 + st * 16 + lm] =
                    (bf16)sv[st][r];

        // O += P V
#pragma unroll
        for (int kc = 0; kc < 64; kc += 32) {
            bf16x8 pf = *reinterpret_cast<const bf16x8*>(
                &ldsP[wave][lm * 72 + kc + koff]);
#pragma unroll
            for (int nt = 0; nt < 4; ++nt) {
                bf16x8 vf = *reinterpret_cast<const bf16x8*>(
                    &ldsVt[(nt * 16 + lm) * 72 + kc + koff]);
                Oacc[nt] = __builtin_amdgcn_mfma_f32_16x16x32_bf16(
                    pf, vf, Oacc[nt], 0, 0, 0);
            }
        }
    }

    // epilogue: O /= l, write bf16 to [M, C] flat
    const int b_ = bh / HH, h = bh % HH;
#pragma unroll
    for (int nt = 0; nt < 4; ++nt)
#pragma unroll
        for (int r = 0; r < 4; ++r) {
            const int q = q0 + quad * 4 + r;
            const int d = nt * 16 + lm;
            const float v = Oacc[nt][r] / l_run[r];
            attn_out[((size_t)(b_ * TT + q)) * CC + h * DD + d] = (bf16)v;
        }
}

// ---------------------------------------------------------------------------
extern "C" void kernel_launch(void* const* d_in, const int* in_sizes, int n_in,
                              void* d_out, int out_size, void* d_ws,
                              size_t ws_size, hipStream_t stream)
{
    // Reference dtypes: float tensors fp32; mask int32 (analytic).
    const float* q  = (const float*)d_in[0];
    const float* k  = (const float*)d_in[1];
    const float* v  = (const float*)d_in[2];
    const float* Wq = (const float*)d_in[4];
    const float* bq = (const float*)d_in[5];
    const float* Wk = (const float*)d_in[6];
    const float* bk = (const float*)d_in[7];
    const float* Wv = (const float*)d_in[8];
    const float* bv = (const float*)d_in[9];
    const float* Wo = (const float*)d_in[10];
    const float* bo = (const float*)d_in[11];
    float* out = (float*)d_out;            // fp32 output [M, C]

    // workspace: Qh | Kh | Vh ([B,H,T,D] bf16) | attn ([M,C] bf16) = 32 MB
    bf16* Qh = (bf16*)d_ws;
    bf16* Kh = Qh + (size_t)MM * CC;
    bf16* Vh = Kh + (size_t)MM * CC;
    bf16* attn = Vh + (size_t)MM * CC;

    const dim3 blk(256);
    gemm_qkv<<<dim3(MM / 128, CC / 128, 3), blk, 0, stream>>>(
        q, k, v, Wq, Wk, Wv, bq, bk, bv, Qh, Kh, Vh);
    attn_fused<<<dim3(TT / 64, BB * HH), blk, 0, stream>>>(Qh, Kh, Vh, attn);
    gemm_oproj<<<dim3(MM / 128, CC / 128), blk, 0, stream>>>(
        attn, Wo, bo, out);
}